// Round 18
// baseline (354.029 us; speedup 1.0000x reference)
//
#include <hip/hip_runtime.h>

// GNNMessagePassing. R18: 3-deep zero-copy gather pipeline in k_tri.
// Evidence: R7 (accidental 2x loads) sustained 2.9 TB/s, R16 (remat storm)
// 3.8 TB/s, vs our 2.43 TB/s at 146us -> k_tri is limited by per-wave
// outstanding misses, not L3 service rate. 3 gather-sets in flight (+50%),
// strictly fresh-load slot assignments (no g0=g1 copies -> no R7 remat).
// Rest identical to R17 (322us: k_tri 146, scatter ~100, GCN ~75).

constexpr int HID = 32;
constexpr int NB = 25;        // buckets
constexpr int BW = 8000;      // edges per bucket (NB*BW = 200000 exactly)
constexpr int CAP = 245760;   // pairs per bucket (mean 240k + ~12 sigma)
constexpr int SB = 16;        // sub-blocks per bucket in k_acc

typedef _Float16 f16;
typedef _Float16 f16x8 __attribute__((ext_vector_type(8)));
typedef float f32x4 __attribute__((ext_vector_type(4)));

#define MFMA16(A, B, C) __builtin_amdgcn_mfma_f32_16x16x32_f16(A, B, C, 0, 0, 0)

// ---------- GCN ----------

__global__ void k_init_deg(float* __restrict__ deg, int n) {
  int i = blockIdx.x * 256 + threadIdx.x;
  if (i < n) deg[i] = 1.0f;  // self-loop
}

__global__ void k_indeg(const int* __restrict__ dst, float* __restrict__ deg, int e) {
  int i = blockIdx.x * 256 + threadIdx.x;
  if (i < e) atomicAdd(&deg[dst[i]], 1.0f);
}

__global__ void k_dinv_agg(float* __restrict__ dinv, float* __restrict__ agg1, int n) {
  int i = blockIdx.x * 256 + threadIdx.x;
  if (i < n) {
    float d = rsqrtf(dinv[i]);
    dinv[i] = d;
    agg1[i] = d * d;
  }
}

__global__ void k_agg1(const int* __restrict__ src, const int* __restrict__ dst,
                       const float* __restrict__ dinv, float* __restrict__ agg1, int e) {
  int i = blockIdx.x * 256 + threadIdx.x;
  if (i < e) atomicAdd(&agg1[dst[i]], dinv[src[i]] * dinv[dst[i]]);
}

__global__ void k_scat(const int* __restrict__ src, const int* __restrict__ dst,
                       const float* __restrict__ dinv, const float* __restrict__ agg1,
                       const float* __restrict__ W1, const float* __restrict__ b1,
                       float* __restrict__ accx1, int e) {
  int gid = blockIdx.x * 256 + threadIdx.x;
  int ei = gid >> 5, k = gid & 31;
  if (ei >= e) return;
  int s = src[ei], d = dst[ei];
  float nrm = dinv[s] * dinv[d];
  float x1 = fmaxf(fmaf(W1[k], agg1[s], b1[k]), 0.0f);
  atomicAdd(&accx1[(size_t)d * HID + k], nrm * x1);
}

// x2 = relu((accx1 + selfterm) @ W2 + b2) -> f16 rows (64B/node = 1 line).
__global__ void k_x2b(const float* __restrict__ accx1, const float* __restrict__ dinv,
                      const float* __restrict__ agg1,
                      const float* __restrict__ W1, const float* __restrict__ b1,
                      const float* __restrict__ W2, const float* __restrict__ b2,
                      f16* __restrict__ x2h, int n) {
  int i = blockIdx.x * 256 + threadIdx.x;
  if (i >= n) return;
  const float* row = accx1 + (size_t)i * HID;
  float di = dinv[i];
  float di2 = di * di;
  float a1 = agg1[i];
  float out[HID];
#pragma unroll
  for (int m = 0; m < HID; m++) out[m] = b2[m];
#pragma unroll 2
  for (int j = 0; j < HID; j++) {
    float v = row[j] + di2 * fmaxf(fmaf(W1[j], a1, b1[j]), 0.0f);
    const float* w = W2 + j * HID;
#pragma unroll
    for (int m = 0; m < HID; m++) out[m] = fmaf(v, w[m], out[m]);
  }
  f16x8* dst = (f16x8*)(x2h + (size_t)i * HID);
#pragma unroll
  for (int qq = 0; qq < 4; qq++) {
    f16x8 v;
#pragma unroll
    for (int j = 0; j < 8; j++) v[j] = (f16)fmaxf(out[8 * qq + j], 0.0f);
    dst[qq] = v;
  }
}

// copy ec -> out_e, and zero the NB bucket cursors
__global__ void k_copy_ec(const float* __restrict__ ec, float* __restrict__ out,
                          int* __restrict__ gcur, int e) {
  int i = blockIdx.x * 256 + threadIdx.x;
  if (i < e) out[i] = ec[i];
  if (i < 32) gcur[i] = 0;
}

// ---------- triangle MLP via MFMA, 3-deep pipelined, NO atomics ----------

struct GathSet {
  f16x8 ha, hb, hc;
  float w0, w1, w2, e0, e1, e2;
};

__global__ __launch_bounds__(256, 3) void k_tri_mfma(
    const float* __restrict__ t12, const float* __restrict__ t13, const float* __restrict__ t23,
    const int* __restrict__ c12p, const int* __restrict__ c13p, const int* __restrict__ c23p,
    const float* __restrict__ ec, const f16* __restrict__ x2h,
    const float* __restrict__ Wm1, const float* __restrict__ bm1,
    const float* __restrict__ Wm2, const float* __restrict__ bm2,
    const float* __restrict__ Wm3, const float* __restrict__ bm3,
    float* __restrict__ o12, int T, int n_waves_total) {
  __shared__ _Float16 htile[4][2][16 * 64];
  __shared__ float dts[4][48];
  __shared__ float tts[4][48];
  const int tid = threadIdx.x;
  const int lane = tid & 63;
  const int wid = tid >> 6;
  const int n_ = lane & 15;
  const int q = lane >> 4;
  const int gwave = blockIdx.x * 4 + wid;
  const int ntiles = (T + 15) >> 4;
  const int s = n_waves_total;

  f16x8 B1[2][4], B2[2][2], B3;
#pragma unroll
  for (int kt = 0; kt < 2; kt++)
#pragma unroll
    for (int nt = 0; nt < 4; nt++) {
      f16x8 f;
#pragma unroll
      for (int j = 0; j < 8; j++) {
        int kp = 32 * kt + 8 * q + j;
        int ks = (kp < 3) ? kp : (kp < 6) ? (32 + kp) : (kp >= 8 && kp < 40) ? (kp - 5) : -1;
        f[j] = (ks >= 0) ? (f16)Wm1[ks * 64 + 16 * nt + n_] : (f16)0.0f;
      }
      B1[kt][nt] = f;
    }
#pragma unroll
  for (int kt = 0; kt < 2; kt++)
#pragma unroll
    for (int nt = 0; nt < 2; nt++) {
      f16x8 f;
#pragma unroll
      for (int j = 0; j < 8; j++)
        f[j] = (f16)Wm2[(32 * kt + 8 * q + j) * 32 + 16 * nt + n_];
      B2[kt][nt] = f;
    }
  {
    f16x8 f;
#pragma unroll
    for (int j = 0; j < 8; j++)
      f[j] = (n_ < 3) ? (f16)Wm3[(8 * q + j) * 3 + n_] : (f16)0.0f;
    B3 = f;
  }
  float bia1[4], bia2[2];
#pragma unroll
  for (int nt = 0; nt < 4; nt++) bia1[nt] = bm1[16 * nt + n_];
#pragma unroll
  for (int nt = 0; nt < 2; nt++) bia2[nt] = bm2[16 * nt + n_];
  const float bia3 = (n_ < 3) ? bm3[n_] : 0.0f;

  _Float16* h1t = htile[wid][0];
  _Float16* h2t = htile[wid][1];
  float* dt = dts[wid];
  float* tt = tts[wid];
  const int sq = (q + 3) & 3;

  struct Corr { int a, b, c; };
  auto load_corr = [&](int tile) -> Corr {
    int tc = tile < ntiles ? tile : ntiles - 1;
    int trc = tc * 16 + n_;
    trc = trc < T ? trc : T - 1;
    Corr cs;
    cs.a = c12p[trc]; cs.b = c13p[trc]; cs.c = c23p[trc];
    return cs;
  };
  auto load_gath = [&](int tile, Corr cs) -> GathSet {
    int tc = tile < ntiles ? tile : ntiles - 1;
    int trc = tc * 16 + n_;
    trc = trc < T ? trc : T - 1;
    GathSet g;
    g.ha = *(const f16x8*)(x2h + (size_t)cs.a * HID + 8 * sq);
    g.hb = *(const f16x8*)(x2h + (size_t)cs.b * HID + 8 * sq);
    g.hc = *(const f16x8*)(x2h + (size_t)cs.c * HID + 8 * sq);
    g.w0 = 0.f; g.w1 = 0.f; g.w2 = 0.f; g.e0 = 0.f; g.e1 = 0.f; g.e2 = 0.f;
    if (q == 0) {
      g.w0 = t12[trc]; g.w1 = t13[trc]; g.w2 = t23[trc];
      g.e0 = ec[cs.a]; g.e1 = ec[cs.b]; g.e2 = ec[cs.c];
    }
    return g;
  };

  auto compute = [&](int tile, const GathSet& g) {
    const int base = tile << 4;
    f16x8 ncf;
#pragma unroll
    for (int j = 0; j < 8; j++) {
      float sv = (float)g.ha[j] + (float)g.hb[j] + (float)g.hc[j];
      ncf[j] = (f16)(sv * (1.0f / 3.0f));
    }
    f16x8 a0, a1;
    if (q == 0) {
      a0[0] = (f16)g.w0; a0[1] = (f16)g.w1; a0[2] = (f16)g.w2;
      a0[3] = (f16)g.e0; a0[4] = (f16)g.e1; a0[5] = (f16)g.e2;
      a0[6] = (f16)0.0f; a0[7] = (f16)0.0f;
      a1 = ncf;
      tt[0 * 16 + n_] = g.w0; tt[1 * 16 + n_] = g.w1; tt[2 * 16 + n_] = g.w2;
    } else {
      a0 = ncf;
#pragma unroll
      for (int j = 0; j < 8; j++) a1[j] = (f16)0.0f;
    }

    f32x4 D1[4];
#pragma unroll
    for (int nt = 0; nt < 4; nt++) {
      f32x4 acc = {0.0f, 0.0f, 0.0f, 0.0f};
      acc = MFMA16(a1, B1[1][nt], acc);
      acc = MFMA16(a0, B1[0][nt], acc);
      D1[nt] = acc;
    }
#pragma unroll
    for (int nt = 0; nt < 4; nt++)
#pragma unroll
      for (int r = 0; r < 4; r++) {
        int m = 4 * q + r;
        float v = fmaxf(D1[nt][r] + bia1[nt], 0.0f);
        h1t[m * 64 + ((16 * nt + n_) ^ ((m & 7) << 3))] = (f16)v;
      }
    f16x8 a2_0 = *(const f16x8*)&h1t[n_ * 64 + ((8 * q) ^ ((n_ & 7) << 3))];
    f16x8 a2_1 = *(const f16x8*)&h1t[n_ * 64 + ((32 + 8 * q) ^ ((n_ & 7) << 3))];

    f32x4 D2[2];
#pragma unroll
    for (int nt = 0; nt < 2; nt++) {
      f32x4 acc = {0.0f, 0.0f, 0.0f, 0.0f};
      acc = MFMA16(a2_1, B2[1][nt], acc);
      acc = MFMA16(a2_0, B2[0][nt], acc);
      D2[nt] = acc;
    }
#pragma unroll
    for (int nt = 0; nt < 2; nt++)
#pragma unroll
      for (int r = 0; r < 4; r++) {
        int m = 4 * q + r;
        float v = fmaxf(D2[nt][r] + bia2[nt], 0.0f);
        h2t[m * 64 + ((16 * nt + n_) ^ ((m & 7) << 3))] = (f16)v;
      }
    f16x8 a3 = *(const f16x8*)&h2t[n_ * 64 + ((8 * q) ^ ((n_ & 7) << 3))];

    f32x4 D3 = {0.0f, 0.0f, 0.0f, 0.0f};
    D3 = MFMA16(a3, B3, D3);

    if (n_ < 3) {
#pragma unroll
      for (int r = 0; r < 4; r++) dt[n_ * 16 + 4 * q + r] = D3[r] + bia3;
    }
    if (lane < 48) {
      int comp = lane >> 4, tr = lane & 15;
      int idx = base + tr;
      if (idx < T)
        o12[(size_t)comp * T + idx] = tt[comp * 16 + tr] - dt[comp * 16 + tr];
    }
  };

  if (gwave >= ntiles) return;
  // ---- 3-deep pipeline: every slot assignment is a FRESH LOAD (no copies) ----
  Corr cT0 = load_corr(gwave);
  Corr cT1 = load_corr(gwave + s);
  GathSet gA = load_gath(gwave, cT0);
  GathSet gB = load_gath(gwave + s, cT1);
  Corr cC = load_corr(gwave + 2 * s);
  Corr cA = load_corr(gwave + 3 * s);
  Corr cB = load_corr(gwave + 4 * s);
  for (int tile = gwave; tile < ntiles; tile += 3 * s) {
    GathSet gC = load_gath(tile + 2 * s, cC);
    cC = load_corr(tile + 5 * s);
    compute(tile, gA);
    gA = load_gath(tile + 3 * s, cA);
    cA = load_corr(tile + 6 * s);
    if (tile + s < ntiles) compute(tile + s, gB);
    gB = load_gath(tile + 4 * s, cB);
    cB = load_corr(tile + 7 * s);
    if (tile + 2 * s < ntiles) compute(tile + 2 * s, gC);
  }
}

// ---------- phase A: bin (corr, t-o) pairs by edge range ----------

__global__ __launch_bounds__(256) void k_bin(
    const int* __restrict__ c12p, const int* __restrict__ c13p, const int* __restrict__ c23p,
    const float* __restrict__ t12, const float* __restrict__ t13, const float* __restrict__ t23,
    const float* __restrict__ o12, unsigned int* __restrict__ pairs,
    int* __restrict__ gcur, float* __restrict__ out_e, int T, int nbatch) {
  __shared__ int cnt[NB], base_[NB], soff[NB + 1];
  __shared__ unsigned int sdata[2048];
  __shared__ unsigned char sbkt[2048];
  const int tid = threadIdx.x;
  const int T3 = 3 * T;

  for (int batch = blockIdx.x; batch < nbatch; batch += gridDim.x) {
    const int j0 = batch * 2048;
    if (tid < NB) cnt[tid] = 0;
    __syncthreads();

    int bk[8], pk[8];
    unsigned int vk[8];
#pragma unroll
    for (int k = 0; k < 8; k++) {
      int j = j0 + k * 256 + tid;
      bk[k] = -1;
      if (j < T3) {
        int idx; float tv;
        if (j < T)          { idx = c12p[j];          tv = t12[j]; }
        else if (j < 2 * T) { idx = c13p[j - T];      tv = t13[j - T]; }
        else                { idx = c23p[j - 2 * T];  tv = t23[j - 2 * T]; }
        float delta = tv - o12[j];  // exact recovery of MLP delta
        int b = idx / BW;
        int li = idx - b * BW;
        unsigned short hb = __builtin_bit_cast(unsigned short, (_Float16)delta);
        bk[k] = b;
        pk[k] = atomicAdd(&cnt[b], 1);
        vk[k] = ((unsigned int)li << 16) | hb;
      }
    }
    __syncthreads();

    if (tid == 0) {
      int run = 0;
      for (int b = 0; b < NB; b++) { soff[b] = run; run += cnt[b]; }
      soff[NB] = run;
    }
    if (tid < NB) base_[tid] = atomicAdd(&gcur[tid], cnt[tid]);
    __syncthreads();

#pragma unroll
    for (int k = 0; k < 8; k++) {
      if (bk[k] >= 0) {
        int p = soff[bk[k]] + pk[k];
        sdata[p] = vk[k];
        sbkt[p] = (unsigned char)bk[k];
      }
    }
    __syncthreads();

    const int total = soff[NB];
    for (int i = tid; i < total; i += 256) {
      int b = sbkt[i];
      int slot = base_[b] + (i - soff[b]);
      unsigned int v = sdata[i];
      if (slot < CAP) {
        pairs[(size_t)b * CAP + slot] = v;
      } else {  // overflow fallback (>=12 sigma; effectively never)
        float d = (float)__builtin_bit_cast(_Float16, (unsigned short)(v & 0xffffu));
        atomicAdd(&out_e[b * BW + (int)(v >> 16)], d);
      }
    }
    __syncthreads();
  }
}

// ---------- phase B: accumulate buckets in LDS, coalesced flush ----------

__global__ __launch_bounds__(256) void k_acc(const unsigned int* __restrict__ pairs,
                                             const int* __restrict__ gcur,
                                             float* __restrict__ out_e) {
  __shared__ float acc[BW];
  const int b = blockIdx.x / SB, sub = blockIdx.x % SB;
  const int tid = threadIdx.x;
  for (int j = tid; j < BW; j += 256) acc[j] = 0.0f;
  __syncthreads();

  int count = gcur[b];
  if (count > CAP) count = CAP;
  int chunk = (count + SB - 1) / SB;
  int lo = sub * chunk;
  int hi = min(count, lo + chunk);
  const unsigned int* p = pairs + (size_t)b * CAP;
  for (int i = lo + tid; i < hi; i += 256) {
    unsigned int v = p[i];
    float d = (float)__builtin_bit_cast(_Float16, (unsigned short)(v & 0xffffu));
    atomicAdd(&acc[v >> 16], d);  // LDS ds_add_f32
  }
  __syncthreads();

  const int base = b * BW;
  for (int j = tid; j < BW; j += 256) {
    float v = acc[j];
    if (v != 0.0f) atomicAdd(&out_e[base + j], v);  // coalesced
  }
}

// ---------- launch ----------

extern "C" void kernel_launch(void* const* d_in, const int* in_sizes, int n_in,
                              void* d_out, int out_size, void* d_ws, size_t ws_size,
                              hipStream_t stream) {
  const float* ec  = (const float*)d_in[0];
  const float* t12 = (const float*)d_in[1];
  const float* t13 = (const float*)d_in[2];
  const float* t23 = (const float*)d_in[3];
  const int* c12 = (const int*)d_in[4];
  const int* c13 = (const int*)d_in[5];
  const int* c23 = (const int*)d_in[6];
  const int* eidx = (const int*)d_in[8];
  const float* W1  = (const float*)d_in[10];
  const float* b1  = (const float*)d_in[11];
  const float* W2  = (const float*)d_in[12];
  const float* b2  = (const float*)d_in[13];
  const float* Wm1 = (const float*)d_in[14];
  const float* bm1 = (const float*)d_in[15];
  const float* Wm2 = (const float*)d_in[16];
  const float* bm2 = (const float*)d_in[17];
  const float* Wm3 = (const float*)d_in[18];
  const float* bm3 = (const float*)d_in[19];

  const int E = in_sizes[0];   // 200000 = NB*BW
  const int T = in_sizes[1];
  const int N = 200000;

  const int* esrc = eidx;
  const int* edst = eidx + E;

  float* dinv  = (float*)d_ws;     // N (deg->rsqrt; gcur reuse)
  float* agg1  = dinv + N;         // N
  float* accx1 = agg1 + N;         // N*HID f32 (pairs after k_x2b)
  f16*   x2h   = (f16*)(accx1 + (size_t)N * HID);  // N*HID f16

  int* gcur = (int*)dinv;
  unsigned int* pairs = (unsigned int*)accx1;

  float* out_e = (float*)d_out;    // E
  float* o12 = out_e + E;          // 3*T contiguous

  auto cdiv = [](int a, int b) { return (a + b - 1) / b; };

  k_init_deg<<<cdiv(N, 256), 256, 0, stream>>>(dinv, N);
  k_indeg<<<cdiv(E, 256), 256, 0, stream>>>(edst, dinv, E);
  k_dinv_agg<<<cdiv(N, 256), 256, 0, stream>>>(dinv, agg1, N);
  k_agg1<<<cdiv(E, 256), 256, 0, stream>>>(esrc, edst, dinv, agg1, E);
  hipMemsetAsync(accx1, 0, (size_t)N * HID * sizeof(float), stream);
  k_scat<<<cdiv(E * HID, 256), 256, 0, stream>>>(esrc, edst, dinv, agg1, W1, b1, accx1, E);
  k_x2b<<<cdiv(N, 256), 256, 0, stream>>>(accx1, dinv, agg1, W1, b1, W2, b2, x2h, N);
  k_copy_ec<<<cdiv(E, 256), 256, 0, stream>>>(ec, out_e, (int*)gcur, E);

  const int nblk = 2048;
  k_tri_mfma<<<nblk, 256, 0, stream>>>(t12, t13, t23, c12, c13, c23, ec, x2h,
                                       Wm1, bm1, Wm2, bm2, Wm3, bm3,
                                       o12, T, nblk * 4);

  const int nbatch = cdiv(3 * T, 2048);
  k_bin<<<1536, 256, 0, stream>>>(c12, c13, c23, t12, t13, t23, o12,
                                  pairs, gcur, out_e, T, nbatch);
  k_acc<<<NB * SB, 256, 0, stream>>>(pairs, gcur, out_e);
}

// Round 19
// 321.068 us; speedup vs baseline: 1.1027x; 1.1027x over previous
//
#include <hip/hip_runtime.h>

// GNNMessagePassing. R19: exact revert to R17 (session best, 322.1us).
// R18's 3-deep pipeline spilled to scratch (WRITE 25->52MB, FETCH +36MB,
// k_tri 146->186): the weight-stationary VGPR set leaves no room for a 3rd
// in-flight gather set. All k_tri levers now falsified with counters:
// occupancy (R16 remat storm), nt-hints (R10 null), 2-deep (R8 null),
// 3-deep (R18 spill), fused binning (R14 10x). Floor: 146us @ 2.43 TB/s.

constexpr int HID = 32;
constexpr int NB = 25;        // buckets
constexpr int BW = 8000;      // edges per bucket (NB*BW = 200000 exactly)
constexpr int CAP = 245760;   // pairs per bucket (mean 240k + ~12 sigma)
constexpr int SB = 16;        // sub-blocks per bucket in k_acc

typedef _Float16 f16;
typedef _Float16 f16x8 __attribute__((ext_vector_type(8)));
typedef float f32x4 __attribute__((ext_vector_type(4)));

#define MFMA16(A, B, C) __builtin_amdgcn_mfma_f32_16x16x32_f16(A, B, C, 0, 0, 0)

// ---------- GCN ----------

__global__ void k_init_deg(float* __restrict__ deg, int n) {
  int i = blockIdx.x * 256 + threadIdx.x;
  if (i < n) deg[i] = 1.0f;  // self-loop
}

__global__ void k_indeg(const int* __restrict__ dst, float* __restrict__ deg, int e) {
  int i = blockIdx.x * 256 + threadIdx.x;
  if (i < e) atomicAdd(&deg[dst[i]], 1.0f);
}

__global__ void k_dinv_agg(float* __restrict__ dinv, float* __restrict__ agg1, int n) {
  int i = blockIdx.x * 256 + threadIdx.x;
  if (i < n) {
    float d = rsqrtf(dinv[i]);
    dinv[i] = d;
    agg1[i] = d * d;
  }
}

__global__ void k_agg1(const int* __restrict__ src, const int* __restrict__ dst,
                       const float* __restrict__ dinv, float* __restrict__ agg1, int e) {
  int i = blockIdx.x * 256 + threadIdx.x;
  if (i < e) atomicAdd(&agg1[dst[i]], dinv[src[i]] * dinv[dst[i]]);
}

__global__ void k_scat(const int* __restrict__ src, const int* __restrict__ dst,
                       const float* __restrict__ dinv, const float* __restrict__ agg1,
                       const float* __restrict__ W1, const float* __restrict__ b1,
                       float* __restrict__ accx1, int e) {
  int gid = blockIdx.x * 256 + threadIdx.x;
  int ei = gid >> 5, k = gid & 31;
  if (ei >= e) return;
  int s = src[ei], d = dst[ei];
  float nrm = dinv[s] * dinv[d];
  float x1 = fmaxf(fmaf(W1[k], agg1[s], b1[k]), 0.0f);
  atomicAdd(&accx1[(size_t)d * HID + k], nrm * x1);
}

// x2 = relu((accx1 + selfterm) @ W2 + b2) -> f16 rows (64B/node = 1 line).
__global__ void k_x2b(const float* __restrict__ accx1, const float* __restrict__ dinv,
                      const float* __restrict__ agg1,
                      const float* __restrict__ W1, const float* __restrict__ b1,
                      const float* __restrict__ W2, const float* __restrict__ b2,
                      f16* __restrict__ x2h, int n) {
  int i = blockIdx.x * 256 + threadIdx.x;
  if (i >= n) return;
  const float* row = accx1 + (size_t)i * HID;
  float di = dinv[i];
  float di2 = di * di;
  float a1 = agg1[i];
  float out[HID];
#pragma unroll
  for (int m = 0; m < HID; m++) out[m] = b2[m];
#pragma unroll 2
  for (int j = 0; j < HID; j++) {
    float v = row[j] + di2 * fmaxf(fmaf(W1[j], a1, b1[j]), 0.0f);
    const float* w = W2 + j * HID;
#pragma unroll
    for (int m = 0; m < HID; m++) out[m] = fmaf(v, w[m], out[m]);
  }
  f16x8* dst = (f16x8*)(x2h + (size_t)i * HID);
#pragma unroll
  for (int qq = 0; qq < 4; qq++) {
    f16x8 v;
#pragma unroll
    for (int j = 0; j < 8; j++) v[j] = (f16)fmaxf(out[8 * qq + j], 0.0f);
    dst[qq] = v;
  }
}

// copy ec -> out_e, and zero the NB bucket cursors
__global__ void k_copy_ec(const float* __restrict__ ec, float* __restrict__ out,
                          int* __restrict__ gcur, int e) {
  int i = blockIdx.x * 256 + threadIdx.x;
  if (i < e) out[i] = ec[i];
  if (i < 32) gcur[i] = 0;
}

// ---------- triangle MLP via MFMA, 2-deep pipelined, NO atomics ----------

struct GathSet {
  f16x8 ha, hb, hc;
  float w0, w1, w2, e0, e1, e2;
};

__global__ __launch_bounds__(256, 3) void k_tri_mfma(
    const float* __restrict__ t12, const float* __restrict__ t13, const float* __restrict__ t23,
    const int* __restrict__ c12p, const int* __restrict__ c13p, const int* __restrict__ c23p,
    const float* __restrict__ ec, const f16* __restrict__ x2h,
    const float* __restrict__ Wm1, const float* __restrict__ bm1,
    const float* __restrict__ Wm2, const float* __restrict__ bm2,
    const float* __restrict__ Wm3, const float* __restrict__ bm3,
    float* __restrict__ o12, int T, int n_waves_total) {
  __shared__ _Float16 htile[4][2][16 * 64];
  __shared__ float dts[4][48];
  __shared__ float tts[4][48];
  const int tid = threadIdx.x;
  const int lane = tid & 63;
  const int wid = tid >> 6;
  const int n_ = lane & 15;
  const int q = lane >> 4;
  const int gwave = blockIdx.x * 4 + wid;
  const int ntiles = (T + 15) >> 4;
  const int s = n_waves_total;

  f16x8 B1[2][4], B2[2][2], B3;
#pragma unroll
  for (int kt = 0; kt < 2; kt++)
#pragma unroll
    for (int nt = 0; nt < 4; nt++) {
      f16x8 f;
#pragma unroll
      for (int j = 0; j < 8; j++) {
        int kp = 32 * kt + 8 * q + j;
        int ks = (kp < 3) ? kp : (kp < 6) ? (32 + kp) : (kp >= 8 && kp < 40) ? (kp - 5) : -1;
        f[j] = (ks >= 0) ? (f16)Wm1[ks * 64 + 16 * nt + n_] : (f16)0.0f;
      }
      B1[kt][nt] = f;
    }
#pragma unroll
  for (int kt = 0; kt < 2; kt++)
#pragma unroll
    for (int nt = 0; nt < 2; nt++) {
      f16x8 f;
#pragma unroll
      for (int j = 0; j < 8; j++)
        f[j] = (f16)Wm2[(32 * kt + 8 * q + j) * 32 + 16 * nt + n_];
      B2[kt][nt] = f;
    }
  {
    f16x8 f;
#pragma unroll
    for (int j = 0; j < 8; j++)
      f[j] = (n_ < 3) ? (f16)Wm3[(8 * q + j) * 3 + n_] : (f16)0.0f;
    B3 = f;
  }
  float bia1[4], bia2[2];
#pragma unroll
  for (int nt = 0; nt < 4; nt++) bia1[nt] = bm1[16 * nt + n_];
#pragma unroll
  for (int nt = 0; nt < 2; nt++) bia2[nt] = bm2[16 * nt + n_];
  const float bia3 = (n_ < 3) ? bm3[n_] : 0.0f;

  _Float16* h1t = htile[wid][0];
  _Float16* h2t = htile[wid][1];
  float* dt = dts[wid];
  float* tt = tts[wid];
  const int sq = (q + 3) & 3;

  struct Corr { int a, b, c; };
  auto load_corr = [&](int tile) -> Corr {
    int tc = tile < ntiles ? tile : ntiles - 1;
    int trc = tc * 16 + n_;
    trc = trc < T ? trc : T - 1;
    Corr cs;
    cs.a = c12p[trc]; cs.b = c13p[trc]; cs.c = c23p[trc];
    return cs;
  };
  auto load_gath = [&](int tile, Corr cs) -> GathSet {
    int tc = tile < ntiles ? tile : ntiles - 1;
    int trc = tc * 16 + n_;
    trc = trc < T ? trc : T - 1;
    GathSet g;
    g.ha = *(const f16x8*)(x2h + (size_t)cs.a * HID + 8 * sq);
    g.hb = *(const f16x8*)(x2h + (size_t)cs.b * HID + 8 * sq);
    g.hc = *(const f16x8*)(x2h + (size_t)cs.c * HID + 8 * sq);
    g.w0 = 0.f; g.w1 = 0.f; g.w2 = 0.f; g.e0 = 0.f; g.e1 = 0.f; g.e2 = 0.f;
    if (q == 0) {
      g.w0 = t12[trc]; g.w1 = t13[trc]; g.w2 = t23[trc];
      g.e0 = ec[cs.a]; g.e1 = ec[cs.b]; g.e2 = ec[cs.c];
    }
    return g;
  };

  auto compute = [&](int tile, const GathSet& g) {
    const int base = tile << 4;
    f16x8 ncf;
#pragma unroll
    for (int j = 0; j < 8; j++) {
      float sv = (float)g.ha[j] + (float)g.hb[j] + (float)g.hc[j];
      ncf[j] = (f16)(sv * (1.0f / 3.0f));
    }
    f16x8 a0, a1;
    if (q == 0) {
      a0[0] = (f16)g.w0; a0[1] = (f16)g.w1; a0[2] = (f16)g.w2;
      a0[3] = (f16)g.e0; a0[4] = (f16)g.e1; a0[5] = (f16)g.e2;
      a0[6] = (f16)0.0f; a0[7] = (f16)0.0f;
      a1 = ncf;
      tt[0 * 16 + n_] = g.w0; tt[1 * 16 + n_] = g.w1; tt[2 * 16 + n_] = g.w2;
    } else {
      a0 = ncf;
#pragma unroll
      for (int j = 0; j < 8; j++) a1[j] = (f16)0.0f;
    }

    f32x4 D1[4];
#pragma unroll
    for (int nt = 0; nt < 4; nt++) {
      f32x4 acc = {0.0f, 0.0f, 0.0f, 0.0f};
      acc = MFMA16(a1, B1[1][nt], acc);
      acc = MFMA16(a0, B1[0][nt], acc);
      D1[nt] = acc;
    }
#pragma unroll
    for (int nt = 0; nt < 4; nt++)
#pragma unroll
      for (int r = 0; r < 4; r++) {
        int m = 4 * q + r;
        float v = fmaxf(D1[nt][r] + bia1[nt], 0.0f);
        h1t[m * 64 + ((16 * nt + n_) ^ ((m & 7) << 3))] = (f16)v;
      }
    f16x8 a2_0 = *(const f16x8*)&h1t[n_ * 64 + ((8 * q) ^ ((n_ & 7) << 3))];
    f16x8 a2_1 = *(const f16x8*)&h1t[n_ * 64 + ((32 + 8 * q) ^ ((n_ & 7) << 3))];

    f32x4 D2[2];
#pragma unroll
    for (int nt = 0; nt < 2; nt++) {
      f32x4 acc = {0.0f, 0.0f, 0.0f, 0.0f};
      acc = MFMA16(a2_1, B2[1][nt], acc);
      acc = MFMA16(a2_0, B2[0][nt], acc);
      D2[nt] = acc;
    }
#pragma unroll
    for (int nt = 0; nt < 2; nt++)
#pragma unroll
      for (int r = 0; r < 4; r++) {
        int m = 4 * q + r;
        float v = fmaxf(D2[nt][r] + bia2[nt], 0.0f);
        h2t[m * 64 + ((16 * nt + n_) ^ ((m & 7) << 3))] = (f16)v;
      }
    f16x8 a3 = *(const f16x8*)&h2t[n_ * 64 + ((8 * q) ^ ((n_ & 7) << 3))];

    f32x4 D3 = {0.0f, 0.0f, 0.0f, 0.0f};
    D3 = MFMA16(a3, B3, D3);

    if (n_ < 3) {
#pragma unroll
      for (int r = 0; r < 4; r++) dt[n_ * 16 + 4 * q + r] = D3[r] + bia3;
    }
    if (lane < 48) {
      int comp = lane >> 4, tr = lane & 15;
      int idx = base + tr;
      if (idx < T)
        o12[(size_t)comp * T + idx] = tt[comp * 16 + tr] - dt[comp * 16 + tr];
    }
  };

  if (gwave >= ntiles) return;
  Corr c0 = load_corr(gwave);
  Corr cA = load_corr(gwave + 2 * s);
  Corr cB = load_corr(gwave + s);
  GathSet gA = load_gath(gwave, c0);
  for (int tile = gwave; tile < ntiles; tile += 2 * s) {
    GathSet gB = load_gath(tile + s, cB);
    cB = load_corr(tile + 3 * s);
    compute(tile, gA);
    gA = load_gath(tile + 2 * s, cA);
    cA = load_corr(tile + 4 * s);
    if (tile + s < ntiles) compute(tile + s, gB);
  }
}

// ---------- phase A: bin (corr, t-o) pairs by edge range ----------

__global__ __launch_bounds__(256) void k_bin(
    const int* __restrict__ c12p, const int* __restrict__ c13p, const int* __restrict__ c23p,
    const float* __restrict__ t12, const float* __restrict__ t13, const float* __restrict__ t23,
    const float* __restrict__ o12, unsigned int* __restrict__ pairs,
    int* __restrict__ gcur, float* __restrict__ out_e, int T, int nbatch) {
  __shared__ int cnt[NB], base_[NB], soff[NB + 1];
  __shared__ unsigned int sdata[2048];
  __shared__ unsigned char sbkt[2048];
  const int tid = threadIdx.x;
  const int T3 = 3 * T;

  for (int batch = blockIdx.x; batch < nbatch; batch += gridDim.x) {
    const int j0 = batch * 2048;
    if (tid < NB) cnt[tid] = 0;
    __syncthreads();

    int bk[8], pk[8];
    unsigned int vk[8];
#pragma unroll
    for (int k = 0; k < 8; k++) {
      int j = j0 + k * 256 + tid;
      bk[k] = -1;
      if (j < T3) {
        int idx; float tv;
        if (j < T)          { idx = c12p[j];          tv = t12[j]; }
        else if (j < 2 * T) { idx = c13p[j - T];      tv = t13[j - T]; }
        else                { idx = c23p[j - 2 * T];  tv = t23[j - 2 * T]; }
        float delta = tv - o12[j];  // exact recovery of MLP delta
        int b = idx / BW;
        int li = idx - b * BW;
        unsigned short hb = __builtin_bit_cast(unsigned short, (_Float16)delta);
        bk[k] = b;
        pk[k] = atomicAdd(&cnt[b], 1);
        vk[k] = ((unsigned int)li << 16) | hb;
      }
    }
    __syncthreads();

    if (tid == 0) {
      int run = 0;
      for (int b = 0; b < NB; b++) { soff[b] = run; run += cnt[b]; }
      soff[NB] = run;
    }
    if (tid < NB) base_[tid] = atomicAdd(&gcur[tid], cnt[tid]);
    __syncthreads();

#pragma unroll
    for (int k = 0; k < 8; k++) {
      if (bk[k] >= 0) {
        int p = soff[bk[k]] + pk[k];
        sdata[p] = vk[k];
        sbkt[p] = (unsigned char)bk[k];
      }
    }
    __syncthreads();

    const int total = soff[NB];
    for (int i = tid; i < total; i += 256) {
      int b = sbkt[i];
      int slot = base_[b] + (i - soff[b]);
      unsigned int v = sdata[i];
      if (slot < CAP) {
        pairs[(size_t)b * CAP + slot] = v;
      } else {  // overflow fallback (>=12 sigma; effectively never)
        float d = (float)__builtin_bit_cast(_Float16, (unsigned short)(v & 0xffffu));
        atomicAdd(&out_e[b * BW + (int)(v >> 16)], d);
      }
    }
    __syncthreads();
  }
}

// ---------- phase B: accumulate buckets in LDS, coalesced flush ----------

__global__ __launch_bounds__(256) void k_acc(const unsigned int* __restrict__ pairs,
                                             const int* __restrict__ gcur,
                                             float* __restrict__ out_e) {
  __shared__ float acc[BW];
  const int b = blockIdx.x / SB, sub = blockIdx.x % SB;
  const int tid = threadIdx.x;
  for (int j = tid; j < BW; j += 256) acc[j] = 0.0f;
  __syncthreads();

  int count = gcur[b];
  if (count > CAP) count = CAP;
  int chunk = (count + SB - 1) / SB;
  int lo = sub * chunk;
  int hi = min(count, lo + chunk);
  const unsigned int* p = pairs + (size_t)b * CAP;
  for (int i = lo + tid; i < hi; i += 256) {
    unsigned int v = p[i];
    float d = (float)__builtin_bit_cast(_Float16, (unsigned short)(v & 0xffffu));
    atomicAdd(&acc[v >> 16], d);  // LDS ds_add_f32
  }
  __syncthreads();

  const int base = b * BW;
  for (int j = tid; j < BW; j += 256) {
    float v = acc[j];
    if (v != 0.0f) atomicAdd(&out_e[base + j], v);  // coalesced
  }
}

// ---------- launch ----------

extern "C" void kernel_launch(void* const* d_in, const int* in_sizes, int n_in,
                              void* d_out, int out_size, void* d_ws, size_t ws_size,
                              hipStream_t stream) {
  const float* ec  = (const float*)d_in[0];
  const float* t12 = (const float*)d_in[1];
  const float* t13 = (const float*)d_in[2];
  const float* t23 = (const float*)d_in[3];
  const int* c12 = (const int*)d_in[4];
  const int* c13 = (const int*)d_in[5];
  const int* c23 = (const int*)d_in[6];
  const int* eidx = (const int*)d_in[8];
  const float* W1  = (const float*)d_in[10];
  const float* b1  = (const float*)d_in[11];
  const float* W2  = (const float*)d_in[12];
  const float* b2  = (const float*)d_in[13];
  const float* Wm1 = (const float*)d_in[14];
  const float* bm1 = (const float*)d_in[15];
  const float* Wm2 = (const float*)d_in[16];
  const float* bm2 = (const float*)d_in[17];
  const float* Wm3 = (const float*)d_in[18];
  const float* bm3 = (const float*)d_in[19];

  const int E = in_sizes[0];   // 200000 = NB*BW
  const int T = in_sizes[1];
  const int N = 200000;

  const int* esrc = eidx;
  const int* edst = eidx + E;

  float* dinv  = (float*)d_ws;     // N (deg->rsqrt; gcur reuse)
  float* agg1  = dinv + N;         // N
  float* accx1 = agg1 + N;         // N*HID f32 (pairs after k_x2b)
  f16*   x2h   = (f16*)(accx1 + (size_t)N * HID);  // N*HID f16

  int* gcur = (int*)dinv;
  unsigned int* pairs = (unsigned int*)accx1;

  float* out_e = (float*)d_out;    // E
  float* o12 = out_e + E;          // 3*T contiguous

  auto cdiv = [](int a, int b) { return (a + b - 1) / b; };

  k_init_deg<<<cdiv(N, 256), 256, 0, stream>>>(dinv, N);
  k_indeg<<<cdiv(E, 256), 256, 0, stream>>>(edst, dinv, E);
  k_dinv_agg<<<cdiv(N, 256), 256, 0, stream>>>(dinv, agg1, N);
  k_agg1<<<cdiv(E, 256), 256, 0, stream>>>(esrc, edst, dinv, agg1, E);
  hipMemsetAsync(accx1, 0, (size_t)N * HID * sizeof(float), stream);
  k_scat<<<cdiv(E * HID, 256), 256, 0, stream>>>(esrc, edst, dinv, agg1, W1, b1, accx1, E);
  k_x2b<<<cdiv(N, 256), 256, 0, stream>>>(accx1, dinv, agg1, W1, b1, W2, b2, x2h, N);
  k_copy_ec<<<cdiv(E, 256), 256, 0, stream>>>(ec, out_e, (int*)gcur, E);

  const int nblk = 2048;
  k_tri_mfma<<<nblk, 256, 0, stream>>>(t12, t13, t23, c12, c13, c23, ec, x2h,
                                       Wm1, bm1, Wm2, bm2, Wm3, bm3,
                                       o12, T, nblk * 4);

  const int nbatch = cdiv(3 * T, 2048);
  k_bin<<<1536, 256, 0, stream>>>(c12, c13, c23, t12, t13, t23, o12,
                                  pairs, gcur, out_e, T, nbatch);
  k_acc<<<NB * SB, 256, 0, stream>>>(pairs, gcur, out_e);
}